// Round 9
// baseline (133.170 us; speedup 1.0000x reference)
//
#include <hip/hip_runtime.h>
#include <math.h>

// MultiWindowAttention B=4,L=2048,H=8,E=D=64 fp32; w = 32<<(h&3).
// Round 9: R6 LDS/double-buffer body + R8 balanced/local schedule +
// swizzled frag-linear K/Q staging (conflict-free ds_write_b128) + VLD=74.
//   S^T = K.Q^T (mfma 16x16x32 bf16) -> C layout == PV A-frag layout.
//   PV  = P.V   (mfma 16x16x16 f16), P stays in registers.
//   Schedule: gx=gid&7 (XCD) owns 4 (b,h) pairs; pr=(it+k4)&3 gives every
//   CU all 4 window classes (20 tile-units/CU, uniform).

#define LL 2048
#define HH 8
#define EE 64
#define DD 64
#define RS (HH * EE)    // 512 floats between consecutive seq positions
#define VLD 74          // sVt row stride in shorts (37 dwords, odd)

typedef __attribute__((ext_vector_type(8))) short short8;
typedef __attribute__((ext_vector_type(4))) float floatx4;
typedef __attribute__((ext_vector_type(4))) _Float16 half4;
typedef __attribute__((ext_vector_type(2))) __fp16 fp16x2;

static __device__ __forceinline__ unsigned f2bf(float f) {
    union { float f; unsigned u; } v; v.f = f;
    return (v.u + 0x7fff + ((v.u >> 16) & 1)) >> 16;   // RNE
}
static __device__ __forceinline__ unsigned pack2(float a, float b) {
    return f2bf(a) | (f2bf(b) << 16);
}
static __device__ __forceinline__ unsigned packh2(float a, float b) {
    union { fp16x2 h; unsigned u; } v;
    v.h = __builtin_amdgcn_cvt_pkrtz(a, b);
    return v.u;
}
// Swizzled frag-linear address (in shorts): block F (16 rows x 8 elems),
// row L. Same transform on store and load; de-conflicts b128 staging writes.
static __device__ __forceinline__ int fragaddr(int F, int L) {
    return F * 128 + ((L + F) & 15) * 8;
}

__global__ __launch_bounds__(256, 4) void mwa_r9(
    const float* __restrict__ Q,
    const float* __restrict__ K,
    const float* __restrict__ V,
    float* __restrict__ O)
{
    const int tid  = threadIdx.x;
    const int lane = tid & 63;
    const int wv   = tid >> 6;
    const int quad = lane >> 4;
    const int l15  = lane & 15;

    // ---- schedule: XCD-locality grouping + CU-de-aliased window classes ----
    const int gid = blockIdx.x;
    const int gx  = gid & 7;             // presumed XCD
    const int s   = gid >> 3;            // 0..127
    const int it  = s & 31;
    const int k4  = s >> 5;              // 0..3
    const int pr  = (it + k4) & 3;       // window class varies per CU slot
    const int b   = gx >> 1;
    const int h   = ((gx & 1) << 2) + pr;
    const int i0  = it << 6;
    const int w   = 32 << (h & 3);

    alignas(16) __shared__ short sK [2][4096];      // K frag-linear swizzled, bf16
    alignas(16) __shared__ short sVt[2][64 * VLD];  // V^T [d][j], f16, padded

    const float* Qb = Q + ((size_t)b * LL * HH + h) * EE;
    const float* Kb = K + ((size_t)b * LL * HH + h) * EE;
    const float* Vb = V + ((size_t)b * LL * HH + h) * DD;
    float*       Ob = O + ((size_t)b * LL * HH + h) * DD;

    // staging decomposition (per thread): row 0..63, 16-short chunk cc
    const int rowp = tid >> 2, ccp = tid & 3, cp = ccp << 4;
    const int jtwp = rowp >> 4, Lp = rowp & 15;
    const int F0p  = (jtwp * 2 + (ccp >> 1)) * 4 + ((ccp & 1) << 1);

    // ---- stage Q (swizzled frag-linear, into sK[0]), grab B-frags ----
    {
        const float4* src = (const float4*)(Qb + (size_t)(i0 + rowp) * RS + cp);
        float4 f0 = src[0], f1 = src[1], f2 = src[2], f3 = src[3];
        uint4 u0 = { pack2(f0.x,f0.y), pack2(f0.z,f0.w), pack2(f1.x,f1.y), pack2(f1.z,f1.w) };
        uint4 u1 = { pack2(f2.x,f2.y), pack2(f2.z,f2.w), pack2(f3.x,f3.y), pack2(f3.z,f3.w) };
        *(uint4*)&sK[0][fragaddr(F0p,     Lp)] = u0;
        *(uint4*)&sK[0][fragaddr(F0p + 1, Lp)] = u1;
    }
    __syncthreads();
    short8 qf0, qf1;
    {
        qf0 = *(const short8*)&sK[0][fragaddr(8 * wv + quad,     l15)];
        qf1 = *(const short8*)&sK[0][fragaddr(8 * wv + 4 + quad, l15)];
    }
    __syncthreads();   // all Q-frag reads done before K staging overwrites

    const int jt_lo = max(0, i0 - w) >> 6;
    const int jt_hi = min(LL - 1, i0 + 63 + w) >> 6;

    // ---- stage first tile into buffer 0 ----
    {
        const int j0 = jt_lo << 6;
        const float4* src = (const float4*)(Kb + (size_t)(j0 + rowp) * RS + cp);
        float4 f0 = src[0], f1 = src[1], f2 = src[2], f3 = src[3];
        float vv[16];
#pragma unroll
        for (int rr = 0; rr < 16; ++rr)
            vv[rr] = Vb[(size_t)(j0 + wv * 16 + rr) * RS + lane];

        uint4 u0 = { pack2(f0.x,f0.y), pack2(f0.z,f0.w), pack2(f1.x,f1.y), pack2(f1.z,f1.w) };
        uint4 u1 = { pack2(f2.x,f2.y), pack2(f2.z,f2.w), pack2(f3.x,f3.y), pack2(f3.z,f3.w) };
        *(uint4*)&sK[0][fragaddr(F0p,     Lp)] = u0;
        *(uint4*)&sK[0][fragaddr(F0p + 1, Lp)] = u1;

        unsigned* dv = (unsigned*)&sVt[0][0];
#pragma unroll
        for (int rr = 0; rr < 8; ++rr)
            dv[lane * (VLD / 2) + wv * 8 + rr] = packh2(vv[2 * rr], vv[2 * rr + 1]);
    }
    __syncthreads();

    floatx4 acc[4] = {};
    float lsum = 0.f;
    const float scale = 0.125f;
    const int iq = i0 + wv * 16 + l15;   // this lane's query row (q = l15)

    for (int jt = jt_lo; jt <= jt_hi; ++jt) {
        const int cur = (jt - jt_lo) & 1;
        const int nxt = cur ^ 1;
        const bool more = jt < jt_hi;
        const int j0 = jt << 6;

        // ---- prefetch next tile into registers ----
        float4 kf0, kf1, kf2, kf3;
        float vv[16];
        if (more) {
            const int jn = (jt + 1) << 6;
            const float4* src = (const float4*)(Kb + (size_t)(jn + rowp) * RS + cp);
            kf0 = src[0]; kf1 = src[1]; kf2 = src[2]; kf3 = src[3];
#pragma unroll
            for (int rr = 0; rr < 16; ++rr)
                vv[rr] = Vb[(size_t)(jn + wv * 16 + rr) * RS + lane];
        }

        // ---- S^T = K.Q^T, then exp -> P^T (stays in registers) ----
        const bool full = ((i0 + 63 - j0) <= w) && ((j0 + 63 - i0) <= w);
        half4 pf[4];
#pragma unroll
        for (int t4 = 0; t4 < 4; ++t4) {
            short8 k0 = *(const short8*)&sK[cur][fragaddr(8 * t4 + quad,     l15)];
            short8 k1 = *(const short8*)&sK[cur][fragaddr(8 * t4 + 4 + quad, l15)];
            floatx4 st = {};
            st = __builtin_amdgcn_mfma_f32_16x16x32_bf16(k0, qf0, st, 0, 0, 0);
            st = __builtin_amdgcn_mfma_f32_16x16x32_bf16(k1, qf1, st, 0, 0, 0);

            float p[4];
            const int jb = j0 + t4 * 16 + quad * 4;
#pragma unroll
            for (int r = 0; r < 4; ++r) {
                float x = st[r] * scale;
                if (!full) {
                    const int di = iq - (jb + r);
                    x = (di <= w && di >= -w) ? x : -INFINITY;
                }
                p[r] = __expf(x);
                lsum += p[r];
            }
            union { half4 v; unsigned u[2]; } pu;
            pu.u[0] = packh2(p[0], p[1]);
            pu.u[1] = packh2(p[2], p[3]);
            pf[t4] = pu.v;
        }

        // ---- O += P.V  (16x16x16 f16; A = P from regs, B = V^T from LDS) ----
#pragma unroll
        for (int nt = 0; nt < 4; ++nt) {
            const short* vbase = &sVt[cur][(nt * 16 + l15) * VLD];
#pragma unroll
            for (int t4 = 0; t4 < 4; ++t4) {
                half4 vf = *(const half4*)(vbase + t4 * 16 + quad * 4);
                acc[nt] = __builtin_amdgcn_mfma_f32_16x16x16f16(pf[t4], vf, acc[nt], 0, 0, 0);
            }
        }

        // ---- write next tile to LDS ----
        if (more) {
            uint4 u0 = { pack2(kf0.x,kf0.y), pack2(kf0.z,kf0.w), pack2(kf1.x,kf1.y), pack2(kf1.z,kf1.w) };
            uint4 u1 = { pack2(kf2.x,kf2.y), pack2(kf2.z,kf2.w), pack2(kf3.x,kf3.y), pack2(kf3.z,kf3.w) };
            *(uint4*)&sK[nxt][fragaddr(F0p,     Lp)] = u0;
            *(uint4*)&sK[nxt][fragaddr(F0p + 1, Lp)] = u1;
            unsigned* dv = (unsigned*)&sVt[nxt][0];
#pragma unroll
            for (int rr = 0; rr < 8; ++rr)
                dv[lane * (VLD / 2) + wv * 8 + rr] = packh2(vv[2 * rr], vv[2 * rr + 1]);
        }
        __syncthreads();
    }

    // ---- epilogue: reduce l across quads, normalize, store ----
    lsum += __shfl_xor(lsum, 16, 64);
    lsum += __shfl_xor(lsum, 32, 64);
    float rinv[4];
#pragma unroll
    for (int r = 0; r < 4; ++r) {
        const float lr = __shfl(lsum, quad * 4 + r, 64);
        rinv[r] = 1.0f / lr;
    }
#pragma unroll
    for (int nt = 0; nt < 4; ++nt) {
#pragma unroll
        for (int r = 0; r < 4; ++r) {
            Ob[(size_t)(i0 + wv * 16 + quad * 4 + r) * RS + nt * 16 + l15]
                = acc[nt][r] * rinv[r];
        }
    }
}

extern "C" void kernel_launch(void* const* d_in, const int* in_sizes, int n_in,
                              void* d_out, int out_size, void* d_ws, size_t ws_size,
                              hipStream_t stream)
{
    const float* Q = (const float*)d_in[0];
    const float* K = (const float*)d_in[1];
    const float* V = (const float*)d_in[2];
    float* O = (float*)d_out;

    dim3 grid(4 * HH * (LL / 64)), block(256);   // 1024 blocks
    hipLaunchKernelGGL(mwa_r9, grid, block, 0, stream, Q, K, V, O);
}